// Round 1
// baseline (182.551 us; speedup 1.0000x reference)
//
#include <hip/hip_runtime.h>
#include <hip/hip_bf16.h>

// Problem constants
#define SS 2048
#define BB 4
#define DD 256
#define HH 8
#define HDD 32
#define FFD 2048
#define MM (SS*BB)   // 8192 rows

typedef __attribute__((ext_vector_type(8))) __bf16 bf16x8;
typedef __attribute__((ext_vector_type(8))) short short8;
typedef __attribute__((ext_vector_type(4))) short short4v;
typedef __attribute__((ext_vector_type(4))) float f32x4;

__device__ __forceinline__ unsigned short f2bf(float f) {
  union { float f; unsigned u; } v; v.f = f;
  unsigned r = v.u + 0x7fffu + ((v.u >> 16) & 1u);
  return (unsigned short)(r >> 16);
}

__device__ __forceinline__ void gload16(const void* g, void* l) {
  __builtin_amdgcn_global_load_lds(
      (const __attribute__((address_space(1))) void*)g,
      (__attribute__((address_space(3))) void*)l, 16, 0, 0);
}

// ---------------- weight convert f32 -> bf16 ----------------
__global__ __launch_bounds__(256)
void cvt_bf16(const float* __restrict__ in, short* __restrict__ out, int n4) {
  int i = blockIdx.x * 256 + threadIdx.x;
  if (i < n4) {
    float4 x = ((const float4*)in)[i];
    short4v o = { (short)f2bf(x.x), (short)f2bf(x.y), (short)f2bf(x.z), (short)f2bf(x.w) };
    ((short4v*)out)[i] = o;
  }
}

// ---------------- LayerNorm over D=256, one wave per row ----------------
template<int NIN, int WF, int WBF>
__global__ __launch_bounds__(256)
void ln_kernel(const float* __restrict__ xa, const float* __restrict__ xb,
               const float* __restrict__ gam, const float* __restrict__ bet,
               float* __restrict__ outf, short* __restrict__ outb)
{
  const int w = threadIdx.x >> 6, l = threadIdx.x & 63;
  const size_t row = (size_t)blockIdx.x * 4 + w;
  float4 x = *(const float4*)&xa[row * 256 + l * 4];
  if (NIN == 2) {
    const float4 y = *(const float4*)&xb[row * 256 + l * 4];
    x.x += y.x; x.y += y.y; x.z += y.z; x.w += y.w;
  }
  float sum = x.x + x.y + x.z + x.w;
  float sq  = x.x*x.x + x.y*x.y + x.z*x.z + x.w*x.w;
#pragma unroll
  for (int off = 32; off > 0; off >>= 1) {
    sum += __shfl_xor(sum, off);
    sq  += __shfl_xor(sq, off);
  }
  const float mu = sum * (1.f / 256.f);
  const float rs = rsqrtf(sq * (1.f / 256.f) - mu * mu + 1e-5f);
  const float4 g4 = *(const float4*)&gam[l * 4];
  const float4 b4 = *(const float4*)&bet[l * 4];
  const float y0 = (x.x - mu) * rs * g4.x + b4.x;
  const float y1 = (x.y - mu) * rs * g4.y + b4.y;
  const float y2 = (x.z - mu) * rs * g4.z + b4.z;
  const float y3 = (x.w - mu) * rs * g4.w + b4.w;
  if (WF) {
    float4 o; o.x = y0; o.y = y1; o.z = y2; o.w = y3;
    *(float4*)&outf[row * 256 + l * 4] = o;
  }
  if (WBF) {
    short4v o = { (short)f2bf(y0), (short)f2bf(y1), (short)f2bf(y2), (short)f2bf(y3) };
    *(short4v*)&outb[row * 256 + l * 4] = o;
  }
}

// ---------------- bf16 GEMM, C = A(MxK) * W(NxK)^T + bias, 128x128 tile ----------------
// EPI 0: qkv scatter (q scaled), bf16 out
// EPI 1: f32 out (out_proj)
// EPI 2: relu, bf16 out (ff1)
// EPI 3: f32 out (ff2)
template<int EPI>
__global__ __launch_bounds__(256)
void gemm_bt(const short* __restrict__ A, const short* __restrict__ W,
             const float* __restrict__ bias, void* __restrict__ out,
             int K, int N)
{
  __shared__ short sA[128 * 32];
  __shared__ short sB[128 * 32];
  const int tid = threadIdx.x;
  const int l  = tid & 63;
  const int w  = tid >> 6;
  const int wr = w >> 1, wc = w & 1;
  const int lr = l & 15, lg = l >> 4;
  const long row0 = (long)blockIdx.y * 128;
  const long col0 = (long)blockIdx.x * 128;
  const int ldsw = (tid & ~63) * 16;   // wave-uniform LDS byte base
  f32x4 acc[4][4] = {};

  for (int k0 = 0; k0 < K; k0 += 32) {
    __syncthreads();
#pragma unroll
    for (int i = 0; i < 2; i++) {
      const int o = (i * 256 + tid) * 16;     // byte offset in 8KB tile
      const int r = o >> 6, cb = o & 63;      // row, byte-in-row (32 bf16 = 64B rows)
      gload16((const char*)A + ((row0 + r) * K + k0) * 2 + cb,
              (char*)sA + i * 4096 + ldsw);
      gload16((const char*)W + ((col0 + r) * K + k0) * 2 + cb,
              (char*)sB + i * 4096 + ldsw);
    }
    __syncthreads();
    bf16x8 af[4], bw[4];
#pragma unroll
    for (int m = 0; m < 4; m++)
      af[m] = *(const bf16x8*)&sA[(wr * 64 + m * 16 + lr) * 32 + lg * 8];
#pragma unroll
    for (int n = 0; n < 4; n++)
      bw[n] = *(const bf16x8*)&sB[(wc * 64 + n * 16 + lr) * 32 + lg * 8];
#pragma unroll
    for (int m = 0; m < 4; m++)
#pragma unroll
      for (int n = 0; n < 4; n++)
        acc[m][n] = __builtin_amdgcn_mfma_f32_16x16x32_bf16(af[m], bw[n], acc[m][n], 0, 0, 0);
  }

#pragma unroll
  for (int m = 0; m < 4; m++) {
    const long rbase = row0 + wr * 64 + m * 16 + lg * 4;
#pragma unroll
    for (int n = 0; n < 4; n++) {
      const long c = col0 + wc * 64 + n * 16 + lr;
      const float bv = bias[c];
#pragma unroll
      for (int j = 0; j < 4; j++) {
        const long r = rbase + j;
        float val = acc[m][n][j] + bv;
        if (EPI == 0) {
          const int part = (int)(c >> 8);
          const int cc = (int)(c & 255);
          const int h = cc >> 5, hd = cc & 31;
          const int bi = (int)(r & 3);
          const int s = (int)(r >> 2);
          if (part == 0) val *= 0.17677669529663687f;  // 1/sqrt(32)
          ((short*)out)[(size_t)part * (MM * DD) + (((size_t)(bi * HH + h) * SS + s) * HDD) + hd] = (short)f2bf(val);
        } else if (EPI == 1) {
          ((float*)out)[(size_t)r * N + c] = val;
        } else if (EPI == 2) {
          ((short*)out)[(size_t)r * N + c] = (short)f2bf(fmaxf(val, 0.f));
        } else {
          ((float*)out)[(size_t)r * N + c] = val;
        }
      }
    }
  }
}

// ---------------- fused tanh-relu attention, per (b,h) pair ----------------
// grid: (32 q-blocks of 64 rows, 32 pairs); block 256 = 4 waves x 16 q-rows
__global__ __launch_bounds__(256)
void attn_kernel(const short* __restrict__ Qb, const short* __restrict__ Kb,
                 const short* __restrict__ Vb, short* __restrict__ Ob)
{
  __shared__ short sVT[32 * 72];      // V^T tile: [d=32][t=64], stride 72 (pad)
  __shared__ short sP[4][16 * 72];    // per-wave P: [q=16][t=64], stride 72
  const int tid = threadIdx.x;
  const int l = tid & 63, w = tid >> 6;
  const int lr = l & 15, lg = l >> 4;
  const int p = blockIdx.y;                 // b*8 + h
  const int q0 = blockIdx.x * 64 + w * 16;  // this wave's q rows
  const size_t base = (size_t)p * SS * HDD;
  const short* Q  = Qb + base;
  const short* Kp = Kb + base;
  const short* Vp = Vb + base;

  const bf16x8 qf = *(const bf16x8*)&Q[(size_t)(q0 + lr) * HDD + lg * 8];
  f32x4 acc0 = {}, acc1 = {};

  for (int t0 = 0; t0 < SS; t0 += 64) {
    __syncthreads();
    { // stage V^T cooperatively: 64 keys x 32 dims
      const int r = tid >> 2, c0 = (tid & 3) * 8;
      const short8 vv = *(const short8*)&Vp[(size_t)(t0 + r) * HDD + c0];
#pragma unroll
      for (int j = 0; j < 8; j++) sVT[(c0 + j) * 72 + r] = vv[j];
    }
    __syncthreads();
    // QK^T (K=32 in one MFMA per 16 keys) + exact relu(tanh(x)) = max(0, 1-2/(e^{2x}+1))
#pragma unroll
    for (int tt = 0; tt < 4; tt++) {
      const bf16x8 kf = *(const bf16x8*)&Kp[(size_t)(t0 + tt * 16 + lr) * HDD + lg * 8];
      f32x4 z = {};
      const f32x4 s = __builtin_amdgcn_mfma_f32_16x16x32_bf16(qf, kf, z, 0, 0, 0);
#pragma unroll
      for (int j = 0; j < 4; j++) {
        const float e = __expf(2.f * s[j]);
        const float wgt = fmaxf(0.f, 1.f - 2.f * __builtin_amdgcn_rcpf(e + 1.f));
        sP[w][(lg * 4 + j) * 72 + tt * 16 + lr] = (short)f2bf(wgt);
      }
    }
    // PV: O[16 q][32 d] += P[16][64] * V[64][32]
#pragma unroll
    for (int kk = 0; kk < 2; kk++) {
      const bf16x8 pf = *(const bf16x8*)&sP[w][lr * 72 + kk * 32 + lg * 8];
      const bf16x8 v0 = *(const bf16x8*)&sVT[lr * 72 + kk * 32 + lg * 8];
      const bf16x8 v1 = *(const bf16x8*)&sVT[(16 + lr) * 72 + kk * 32 + lg * 8];
      acc0 = __builtin_amdgcn_mfma_f32_16x16x32_bf16(pf, v0, acc0, 0, 0, 0);
      acc1 = __builtin_amdgcn_mfma_f32_16x16x32_bf16(pf, v1, acc1, 0, 0, 0);
    }
  }
  const int bi = p >> 3, h = p & 7;
#pragma unroll
  for (int j = 0; j < 4; j++) {
    const int sr = q0 + lg * 4 + j;
    short* dst = Ob + ((size_t)(sr * BB + bi) * DD) + h * HDD;
    dst[lr]      = (short)f2bf(acc0[j]);
    dst[16 + lr] = (short)f2bf(acc1[j]);
  }
}

// ---------------- launch ----------------
extern "C" void kernel_launch(void* const* d_in, const int* in_sizes, int n_in,
                              void* d_out, int out_size, void* d_ws, size_t ws_size,
                              hipStream_t stream) {
  const float* features   = (const float*)d_in[0];
  const float* ln_g       = (const float*)d_in[1];
  const float* ln_b       = (const float*)d_in[2];
  const float* in_proj_w  = (const float*)d_in[3];
  const float* in_proj_b  = (const float*)d_in[4];
  const float* out_proj_w = (const float*)d_in[5];
  const float* out_proj_b = (const float*)d_in[6];
  const float* w1 = (const float*)d_in[7];
  const float* b1 = (const float*)d_in[8];
  const float* w2 = (const float*)d_in[9];
  const float* b2 = (const float*)d_in[10];

  char* ws = (char*)d_ws;
  const size_t MB = 1024 * 1024;
  float* lnx_f  = (float*)(ws + 0);        // 8MB  [0,8)
  short* lnx_b  = (short*)(ws + 8 * MB);   // 4MB  [8,12)  (reused as attn_out later)
  short* qkv    = (short*)(ws + 12 * MB);  // 12MB [12,24) q,k,v each 2097152 elems
  short* attn_o = lnx_b;                   // reuse after QKV GEMM consumed lnx_b
  float* proj   = (float*)(ws + 12 * MB);  // 8MB  [12,20) reuse q/k after attention
  float* r1_f   = (float*)(ws + 20 * MB);  // 8MB  [20,28) reuse v
  short* r1_b   = (short*)(ws + 28 * MB);  // 4MB  [28,32)
  short* h1     = (short*)(ws + 32 * MB);  // 32MB [32,64)
  float* ffb    = proj;                    // reuse [12,20) after r1 LN
  short* wqkv_b = (short*)(ws + 64 * MB);  // 768*256
  short* wout_b = wqkv_b + 768 * 256;      // 256*256
  short* w1_b   = wout_b + 256 * 256;      // 2048*256
  short* w2_b   = w1_b + 2048 * 256;       // 256*2048

  // 1) weight converts
  cvt_bf16<<<192, 256, 0, stream>>>(in_proj_w,  wqkv_b, 768 * 256 / 4);
  cvt_bf16<<<64,  256, 0, stream>>>(out_proj_w, wout_b, 256 * 256 / 4);
  cvt_bf16<<<512, 256, 0, stream>>>(w1, w1_b, 2048 * 256 / 4);
  cvt_bf16<<<512, 256, 0, stream>>>(w2, w2_b, 256 * 2048 / 4);

  // 2) ln_x = LN(features)
  ln_kernel<1, 1, 1><<<2048, 256, 0, stream>>>(features, nullptr, ln_g, ln_b, lnx_f, lnx_b);

  // 3) qkv = ln_x @ in_proj_w^T + b  (scatter to per-(b,h) q/k/v, q scaled)
  gemm_bt<0><<<dim3(6, 64), 256, 0, stream>>>(lnx_b, wqkv_b, in_proj_b, qkv, 256, 768);

  // 4) attention (relu(tanh(qk^T)) @ v), per (b,h)
  attn_kernel<<<dim3(32, 32), 256, 0, stream>>>(qkv, qkv + 2097152, qkv + 2 * 2097152, attn_o);

  // 5) proj = attn @ out_proj_w^T + b
  gemm_bt<1><<<dim3(2, 64), 256, 0, stream>>>(attn_o, wout_b, out_proj_b, proj, 256, 256);

  // 6) r1 = LN(ln_x + proj)
  ln_kernel<2, 1, 1><<<2048, 256, 0, stream>>>(lnx_f, proj, ln_g, ln_b, r1_f, r1_b);

  // 7) h1 = relu(r1 @ w1^T + b1)
  gemm_bt<2><<<dim3(16, 64), 256, 0, stream>>>(r1_b, w1_b, b1, h1, 256, 2048);

  // 8) ff = h1 @ w2^T + b2
  gemm_bt<3><<<dim3(2, 64), 256, 0, stream>>>(h1, w2_b, b2, ffb, 2048, 256);

  // 9) out = LN(r1 + ff)
  ln_kernel<2, 1, 0><<<2048, 256, 0, stream>>>(r1_f, ffb, ln_g, ln_b, (float*)d_out, nullptr);
}

// Round 2
// 174.101 us; speedup vs baseline: 1.0485x; 1.0485x over previous
//
#include <hip/hip_runtime.h>
#include <hip/hip_bf16.h>

// Problem constants
#define SS 2048
#define BB 4
#define DD 256
#define HH 8
#define HDD 32
#define FFD 2048
#define MM (SS*BB)   // 8192 rows

typedef __attribute__((ext_vector_type(8))) __bf16 bf16x8;
typedef __attribute__((ext_vector_type(4))) __bf16 bf16x4;
typedef __attribute__((ext_vector_type(8))) short short8;
typedef __attribute__((ext_vector_type(4))) short short4v;
typedef __attribute__((ext_vector_type(4))) float f32x4;

__device__ __forceinline__ unsigned short f2bf(float f) {
  union { float f; unsigned u; } v; v.f = f;
  unsigned r = v.u + 0x7fffu + ((v.u >> 16) & 1u);
  return (unsigned short)(r >> 16);
}

__device__ __forceinline__ void gload16(const void* g, void* l) {
  __builtin_amdgcn_global_load_lds(
      (const __attribute__((address_space(1))) void*)g,
      (__attribute__((address_space(3))) void*)l, 16, 0, 0);
}

// ---------------- weight convert f32 -> bf16 ----------------
__global__ __launch_bounds__(256)
void cvt_bf16(const float* __restrict__ in, short* __restrict__ out, int n4) {
  int i = blockIdx.x * 256 + threadIdx.x;
  if (i < n4) {
    float4 x = ((const float4*)in)[i];
    short4v o = { (short)f2bf(x.x), (short)f2bf(x.y), (short)f2bf(x.z), (short)f2bf(x.w) };
    ((short4v*)out)[i] = o;
  }
}

// ---------------- LayerNorm over D=256, one wave per row ----------------
template<int NIN, int WF, int WBF>
__global__ __launch_bounds__(256)
void ln_kernel(const float* __restrict__ xa, const float* __restrict__ xb,
               const float* __restrict__ gam, const float* __restrict__ bet,
               float* __restrict__ outf, short* __restrict__ outb)
{
  const int w = threadIdx.x >> 6, l = threadIdx.x & 63;
  const size_t row = (size_t)blockIdx.x * 4 + w;
  float4 x = *(const float4*)&xa[row * 256 + l * 4];
  if (NIN == 2) {
    const float4 y = *(const float4*)&xb[row * 256 + l * 4];
    x.x += y.x; x.y += y.y; x.z += y.z; x.w += y.w;
  }
  float sum = x.x + x.y + x.z + x.w;
  float sq  = x.x*x.x + x.y*x.y + x.z*x.z + x.w*x.w;
#pragma unroll
  for (int off = 32; off > 0; off >>= 1) {
    sum += __shfl_xor(sum, off);
    sq  += __shfl_xor(sq, off);
  }
  const float mu = sum * (1.f / 256.f);
  const float rs = rsqrtf(sq * (1.f / 256.f) - mu * mu + 1e-5f);
  const float4 g4 = *(const float4*)&gam[l * 4];
  const float4 b4 = *(const float4*)&bet[l * 4];
  const float y0 = (x.x - mu) * rs * g4.x + b4.x;
  const float y1 = (x.y - mu) * rs * g4.y + b4.y;
  const float y2 = (x.z - mu) * rs * g4.z + b4.z;
  const float y3 = (x.w - mu) * rs * g4.w + b4.w;
  if (WF) {
    float4 o; o.x = y0; o.y = y1; o.z = y2; o.w = y3;
    *(float4*)&outf[row * 256 + l * 4] = o;
  }
  if (WBF) {
    short4v o = { (short)f2bf(y0), (short)f2bf(y1), (short)f2bf(y2), (short)f2bf(y3) };
    *(short4v*)&outb[row * 256 + l * 4] = o;
  }
}

// ---------------- bf16 GEMM, C = A(MxK) * W(NxK)^T + bias, 128x128 tile ----------------
// EPI 0: qkv scatter (q scaled, v transposed), bf16 out
// EPI 1: f32 out (out_proj)
// EPI 2: relu, bf16 out (ff1)
// EPI 3: f32 out (ff2)
template<int EPI>
__global__ __launch_bounds__(256)
void gemm_bt(const short* __restrict__ A, const short* __restrict__ W,
             const float* __restrict__ bias, void* __restrict__ out,
             int K, int N)
{
  __shared__ short sA[128 * 32];
  __shared__ short sB[128 * 32];
  const int tid = threadIdx.x;
  const int l  = tid & 63;
  const int w  = tid >> 6;
  const int wr = w >> 1, wc = w & 1;
  const int lr = l & 15, lg = l >> 4;
  const long row0 = (long)blockIdx.y * 128;
  const long col0 = (long)blockIdx.x * 128;
  const int ldsw = (tid & ~63) * 16;   // wave-uniform LDS byte base
  f32x4 acc[4][4] = {};

  for (int k0 = 0; k0 < K; k0 += 32) {
    __syncthreads();
#pragma unroll
    for (int i = 0; i < 2; i++) {
      const int o = (i * 256 + tid) * 16;     // byte offset in 8KB tile
      const int r = o >> 6, cb = o & 63;      // row, byte-in-row (32 bf16 = 64B rows)
      gload16((const char*)A + ((row0 + r) * K + k0) * 2 + cb,
              (char*)sA + i * 4096 + ldsw);
      gload16((const char*)W + ((col0 + r) * K + k0) * 2 + cb,
              (char*)sB + i * 4096 + ldsw);
    }
    __syncthreads();
    bf16x8 af[4], bw[4];
#pragma unroll
    for (int m = 0; m < 4; m++)
      af[m] = *(const bf16x8*)&sA[(wr * 64 + m * 16 + lr) * 32 + lg * 8];
#pragma unroll
    for (int n = 0; n < 4; n++)
      bw[n] = *(const bf16x8*)&sB[(wc * 64 + n * 16 + lr) * 32 + lg * 8];
#pragma unroll
    for (int m = 0; m < 4; m++)
#pragma unroll
      for (int n = 0; n < 4; n++)
        acc[m][n] = __builtin_amdgcn_mfma_f32_16x16x32_bf16(af[m], bw[n], acc[m][n], 0, 0, 0);
  }

#pragma unroll
  for (int m = 0; m < 4; m++) {
    const long rbase = row0 + wr * 64 + m * 16 + lg * 4;
#pragma unroll
    for (int n = 0; n < 4; n++) {
      const long c = col0 + wc * 64 + n * 16 + lr;
      const float bv = bias[c];
#pragma unroll
      for (int j = 0; j < 4; j++) {
        const long r = rbase + j;
        float val = acc[m][n][j] + bv;
        if (EPI == 0) {
          const int part = (int)(c >> 8);
          const int cc = (int)(c & 255);
          const int h = cc >> 5, hd = cc & 31;
          const int bi = (int)(r & 3);
          const int s = (int)(r >> 2);
          const int bh = bi * HH + h;
          if (part == 0) val *= 0.17677669529663687f;  // 1/sqrt(32)
          size_t idx;
          if (part == 2) {  // V transposed: [bh][hd][s]
            idx = (size_t)2 * (MM * DD) + ((size_t)bh * HDD + hd) * SS + s;
          } else {          // Q/K: [bh][s][hd]
            idx = (size_t)part * (MM * DD) + ((size_t)bh * SS + s) * HDD + hd;
          }
          ((short*)out)[idx] = (short)f2bf(val);
        } else if (EPI == 1) {
          ((float*)out)[(size_t)r * N + c] = val;
        } else if (EPI == 2) {
          ((short*)out)[(size_t)r * N + c] = (short)f2bf(fmaxf(val, 0.f));
        } else {
          ((float*)out)[(size_t)r * N + c] = val;
        }
      }
    }
  }
}

// ---------------- fused tanh-relu attention, per (b,h) pair ----------------
// grid: (16 q-blocks of 128 rows, 32 pairs); block 256 = 4 waves x 32 q-rows
// No barriers: per-wave P in LDS; V^T read directly from global; K/V reg dbuf.
__global__ __launch_bounds__(256)
void attn_kernel(const short* __restrict__ Qb, const short* __restrict__ Kb,
                 const short* __restrict__ VTb, short* __restrict__ Ob)
{
  __shared__ short sP[4][32 * 72];   // per-wave P: [q=32][t=64], stride 72
  const int tid = threadIdx.x;
  const int l = tid & 63, w = tid >> 6;
  const int lr = l & 15, lg = l >> 4;
  const int p = blockIdx.y;                   // b*8 + h
  const int q0 = blockIdx.x * 128 + w * 32;   // this wave's 32 q rows
  const size_t base = (size_t)p * SS * HDD;
  const short* Q  = Qb + base;
  const short* Kp = Kb + base;
  const short* VT = VTb + base;               // [d=32][s=2048]
  short* sPw = &sP[w][0];

  const bf16x8 qf0 = *(const bf16x8*)&Q[(size_t)(q0 + lr) * HDD + lg * 8];
  const bf16x8 qf1 = *(const bf16x8*)&Q[(size_t)(q0 + 16 + lr) * HDD + lg * 8];
  f32x4 acc00 = {}, acc01 = {}, acc10 = {}, acc11 = {};  // [r16][dtile]

  auto loadK = [&](int t0, bf16x8* kf) {
#pragma unroll
    for (int tt = 0; tt < 4; tt++)
      kf[tt] = *(const bf16x8*)&Kp[(size_t)(t0 + tt * 16 + lr) * HDD + lg * 8];
  };
  auto loadV = [&](int t0, bf16x8* vf) {
#pragma unroll
    for (int i = 0; i < 4; i++) {   // i = dt*2 + kk
      const int dt = i >> 1, kk = i & 1;
      vf[i] = *(const bf16x8*)&VT[(size_t)(dt * 16 + lr) * SS + t0 + kk * 32 + lg * 8];
    }
  };
  auto step = [&](const bf16x8* kf, const bf16x8* vf) {
    // QK^T swapped: D[key][q], key = tt*16 + lg*4 + j, q = r16*16 + lr
#pragma unroll
    for (int r16 = 0; r16 < 2; r16++) {
      const bf16x8 qf = r16 ? qf1 : qf0;
#pragma unroll
      for (int tt = 0; tt < 4; tt++) {
        f32x4 z = {};
        const f32x4 s = __builtin_amdgcn_mfma_f32_16x16x32_bf16(kf[tt], qf, z, 0, 0, 0);
        bf16x4 pv;
#pragma unroll
        for (int j = 0; j < 4; j++) {
          const float e = __expf(2.f * s[j]);
          const float t = 1.f - 2.f * __builtin_amdgcn_rcpf(e + 1.f);
          pv[j] = (__bf16)fmaxf(t, 0.f);
        }
        *(bf16x4*)&sPw[(r16 * 16 + lr) * 72 + tt * 16 + lg * 4] = pv;
      }
    }
    // PV: O[q][d] += P[q][64] * V[64][d]
#pragma unroll
    for (int r16 = 0; r16 < 2; r16++) {
#pragma unroll
      for (int kk = 0; kk < 2; kk++) {
        const bf16x8 pf = *(const bf16x8*)&sPw[(r16 * 16 + lr) * 72 + kk * 32 + lg * 8];
        if (r16 == 0) {
          acc00 = __builtin_amdgcn_mfma_f32_16x16x32_bf16(pf, vf[0 + kk], acc00, 0, 0, 0);
          acc01 = __builtin_amdgcn_mfma_f32_16x16x32_bf16(pf, vf[2 + kk], acc01, 0, 0, 0);
        } else {
          acc10 = __builtin_amdgcn_mfma_f32_16x16x32_bf16(pf, vf[0 + kk], acc10, 0, 0, 0);
          acc11 = __builtin_amdgcn_mfma_f32_16x16x32_bf16(pf, vf[2 + kk], acc11, 0, 0, 0);
        }
      }
    }
  };

  bf16x8 kA[4], vA[4], kB[4], vB[4];
  loadK(0, kA); loadV(0, vA);
  for (int t0 = 0; t0 < SS; t0 += 128) {
    loadK(t0 + 64, kB); loadV(t0 + 64, vB);
    step(kA, vA);
    const int tn = (t0 + 128 < SS) ? t0 + 128 : 0;
    loadK(tn, kA); loadV(tn, vA);
    step(kB, vB);
  }

  const int bi = p >> 3, h = p & 7;
#pragma unroll
  for (int r16 = 0; r16 < 2; r16++) {
#pragma unroll
    for (int j = 0; j < 4; j++) {
      const int sr = q0 + r16 * 16 + lg * 4 + j;
      __bf16* dst = (__bf16*)(Ob + ((size_t)(sr * BB + bi) * DD) + h * HDD);
      dst[lr]      = (__bf16)(r16 ? acc10[j] : acc00[j]);
      dst[16 + lr] = (__bf16)(r16 ? acc11[j] : acc01[j]);
    }
  }
}

// ---------------- launch ----------------
extern "C" void kernel_launch(void* const* d_in, const int* in_sizes, int n_in,
                              void* d_out, int out_size, void* d_ws, size_t ws_size,
                              hipStream_t stream) {
  const float* features   = (const float*)d_in[0];
  const float* ln_g       = (const float*)d_in[1];
  const float* ln_b       = (const float*)d_in[2];
  const float* in_proj_w  = (const float*)d_in[3];
  const float* in_proj_b  = (const float*)d_in[4];
  const float* out_proj_w = (const float*)d_in[5];
  const float* out_proj_b = (const float*)d_in[6];
  const float* w1 = (const float*)d_in[7];
  const float* b1 = (const float*)d_in[8];
  const float* w2 = (const float*)d_in[9];
  const float* b2 = (const float*)d_in[10];

  char* ws = (char*)d_ws;
  const size_t MB = 1024 * 1024;
  float* lnx_f  = (float*)(ws + 0);        // 8MB  [0,8)
  short* lnx_b  = (short*)(ws + 8 * MB);   // 4MB  [8,12)  (reused as attn_out later)
  short* qkv    = (short*)(ws + 12 * MB);  // 12MB [12,24) q,k (per-bh rows), v^T
  short* attn_o = lnx_b;                   // reuse after QKV GEMM consumed lnx_b
  float* proj   = (float*)(ws + 12 * MB);  // 8MB  [12,20) reuse q/k after attention
  float* r1_f   = (float*)(ws + 20 * MB);  // 8MB  [20,28) reuse v
  short* r1_b   = (short*)(ws + 28 * MB);  // 4MB  [28,32)
  short* h1     = (short*)(ws + 32 * MB);  // 32MB [32,64)
  float* ffb    = proj;                    // reuse [12,20) after r1 LN
  short* wqkv_b = (short*)(ws + 64 * MB);  // 768*256
  short* wout_b = wqkv_b + 768 * 256;      // 256*256
  short* w1_b   = wout_b + 256 * 256;      // 2048*256
  short* w2_b   = w1_b + 2048 * 256;       // 256*2048

  // 1) weight converts
  cvt_bf16<<<192, 256, 0, stream>>>(in_proj_w,  wqkv_b, 768 * 256 / 4);
  cvt_bf16<<<64,  256, 0, stream>>>(out_proj_w, wout_b, 256 * 256 / 4);
  cvt_bf16<<<512, 256, 0, stream>>>(w1, w1_b, 2048 * 256 / 4);
  cvt_bf16<<<512, 256, 0, stream>>>(w2, w2_b, 256 * 2048 / 4);

  // 2) ln_x = LN(features)
  ln_kernel<1, 1, 1><<<2048, 256, 0, stream>>>(features, nullptr, ln_g, ln_b, lnx_f, lnx_b);

  // 3) qkv = ln_x @ in_proj_w^T + b  (scatter q/k per-(b,h), v transposed, q scaled)
  gemm_bt<0><<<dim3(6, 64), 256, 0, stream>>>(lnx_b, wqkv_b, in_proj_b, qkv, 256, 768);

  // 4) attention (relu(tanh(qk^T)) @ v), per (b,h), barrier-free
  attn_kernel<<<dim3(16, 32), 256, 0, stream>>>(qkv, qkv + 2097152, qkv + 2 * 2097152, attn_o);

  // 5) proj = attn @ out_proj_w^T + b
  gemm_bt<1><<<dim3(2, 64), 256, 0, stream>>>(attn_o, wout_b, out_proj_b, proj, 256, 256);

  // 6) r1 = LN(ln_x + proj)
  ln_kernel<2, 1, 1><<<2048, 256, 0, stream>>>(lnx_f, proj, ln_g, ln_b, r1_f, r1_b);

  // 7) h1 = relu(r1 @ w1^T + b1)
  gemm_bt<2><<<dim3(16, 64), 256, 0, stream>>>(r1_b, w1_b, b1, h1, 256, 2048);

  // 8) ff = h1 @ w2^T + b2
  gemm_bt<3><<<dim3(2, 64), 256, 0, stream>>>(h1, w2_b, b2, ffb, 2048, 256);

  // 9) out = LN(r1 + ff)
  ln_kernel<2, 1, 0><<<2048, 256, 0, stream>>>(r1_f, ffb, ln_g, ln_b, (float*)d_out, nullptr);
}

// Round 3
// 171.979 us; speedup vs baseline: 1.0615x; 1.0123x over previous
//
#include <hip/hip_runtime.h>
#include <hip/hip_bf16.h>

// Problem constants
#define SS 2048
#define BB 4
#define DD 256
#define HH 8
#define HDD 32
#define FFD 2048
#define MM (SS*BB)   // 8192 rows

typedef __attribute__((ext_vector_type(8))) __bf16 bf16x8;
typedef __attribute__((ext_vector_type(2))) __bf16 bf16x2;
typedef __attribute__((ext_vector_type(4))) short short4v;
typedef __attribute__((ext_vector_type(4))) float f32x4;
typedef __attribute__((ext_vector_type(16))) float f32x16;
typedef __attribute__((ext_vector_type(2))) unsigned uint2v;
typedef __attribute__((ext_vector_type(4))) unsigned uint4v;

__device__ __forceinline__ unsigned short f2bf(float f) {
  union { float f; unsigned u; } v; v.f = f;
  unsigned r = v.u + 0x7fffu + ((v.u >> 16) & 1u);
  return (unsigned short)(r >> 16);
}

__device__ __forceinline__ unsigned pk2(float a, float b) {
  bf16x2 t; t[0] = (__bf16)a; t[1] = (__bf16)b;
  return __builtin_bit_cast(unsigned, t);
}

__device__ __forceinline__ void gload16(const void* g, void* l) {
  __builtin_amdgcn_global_load_lds(
      (const __attribute__((address_space(1))) void*)g,
      (__attribute__((address_space(3))) void*)l, 16, 0, 0);
}

// ---------------- weight convert f32 -> bf16 ----------------
__global__ __launch_bounds__(256)
void cvt_bf16(const float* __restrict__ in, short* __restrict__ out, int n4) {
  int i = blockIdx.x * 256 + threadIdx.x;
  if (i < n4) {
    float4 x = ((const float4*)in)[i];
    short4v o = { (short)f2bf(x.x), (short)f2bf(x.y), (short)f2bf(x.z), (short)f2bf(x.w) };
    ((short4v*)out)[i] = o;
  }
}

// ---------------- LayerNorm over D=256, one wave per row ----------------
template<int NIN, int WF, int WBF>
__global__ __launch_bounds__(256)
void ln_kernel(const float* __restrict__ xa, const float* __restrict__ xb,
               const float* __restrict__ xc,
               const float* __restrict__ gam, const float* __restrict__ bet,
               float* __restrict__ outf, short* __restrict__ outb)
{
  const int w = threadIdx.x >> 6, l = threadIdx.x & 63;
  const size_t row = (size_t)blockIdx.x * 4 + w;
  float4 x = *(const float4*)&xa[row * 256 + l * 4];
  if (NIN >= 2) {
    const float4 y = *(const float4*)&xb[row * 256 + l * 4];
    x.x += y.x; x.y += y.y; x.z += y.z; x.w += y.w;
  }
  if (NIN >= 3) {
    const float4 y = *(const float4*)&xc[row * 256 + l * 4];
    x.x += y.x; x.y += y.y; x.z += y.z; x.w += y.w;
  }
  float sum = x.x + x.y + x.z + x.w;
  float sq  = x.x*x.x + x.y*x.y + x.z*x.z + x.w*x.w;
#pragma unroll
  for (int off = 32; off > 0; off >>= 1) {
    sum += __shfl_xor(sum, off);
    sq  += __shfl_xor(sq, off);
  }
  const float mu = sum * (1.f / 256.f);
  const float rs = rsqrtf(sq * (1.f / 256.f) - mu * mu + 1e-5f);
  const float4 g4 = *(const float4*)&gam[l * 4];
  const float4 b4 = *(const float4*)&bet[l * 4];
  const float y0 = (x.x - mu) * rs * g4.x + b4.x;
  const float y1 = (x.y - mu) * rs * g4.y + b4.y;
  const float y2 = (x.z - mu) * rs * g4.z + b4.z;
  const float y3 = (x.w - mu) * rs * g4.w + b4.w;
  if (WF) {
    float4 o; o.x = y0; o.y = y1; o.z = y2; o.w = y3;
    *(float4*)&outf[row * 256 + l * 4] = o;
  }
  if (WBF) {
    short4v o = { (short)f2bf(y0), (short)f2bf(y1), (short)f2bf(y2), (short)f2bf(y3) };
    *(short4v*)&outb[row * 256 + l * 4] = o;
  }
}

// ---------------- bf16 GEMM, C = A(MxK) * W(NxK)^T + bias, BMx128 tile ----------------
// EPI 0: qkv scatter (q scaled, v transposed), bf16 out
// EPI 1: f32 out (out_proj)
// EPI 2: relu, bf16 out (ff1)
// EPI 3: f32 out, split-K via blockIdx.z (partial 1 -> out2, no bias)
template<int EPI, int BM>
__global__ __launch_bounds__(256)
void gemm_bt(const short* __restrict__ A, const short* __restrict__ W,
             const float* __restrict__ bias, void* __restrict__ out,
             void* __restrict__ out2, int K, int N, int Ksub)
{
  __shared__ short sA[BM * 32];
  __shared__ short sB[128 * 32];
  const int tid = threadIdx.x;
  const int l  = tid & 63;
  const int w  = tid >> 6;
  const int wr = w >> 1, wc = w & 1;
  const int lr = l & 15, lg = l >> 4;
  const long row0 = (long)blockIdx.y * BM;
  const long col0 = (long)blockIdx.x * 128;
  const int kz = blockIdx.z;
  const int kbeg = kz * Ksub;
  const int ldsw = (tid & ~63) * 16;   // wave-uniform LDS byte base
  constexpr int MR = BM / 32;          // m-frags per wave
  f32x4 acc[MR][4] = {};

  for (int k0 = kbeg; k0 < kbeg + Ksub; k0 += 32) {
    __syncthreads();
#pragma unroll
    for (int i = 0; i < BM / 64; i++) {
      const int o = (i * 256 + tid) * 16;     // byte offset in A tile
      const int r = o >> 6, cb = o & 63;      // row, byte-in-row (32 bf16 = 64B rows)
      gload16((const char*)A + ((row0 + r) * K + k0) * 2 + cb,
              (char*)sA + i * 4096 + ldsw);
    }
#pragma unroll
    for (int i = 0; i < 2; i++) {
      const int o = (i * 256 + tid) * 16;
      const int r = o >> 6, cb = o & 63;
      gload16((const char*)W + ((col0 + r) * K + k0) * 2 + cb,
              (char*)sB + i * 4096 + ldsw);
    }
    __syncthreads();
    bf16x8 af[MR], bw[4];
#pragma unroll
    for (int m = 0; m < MR; m++)
      af[m] = *(const bf16x8*)&sA[(wr * (BM/2) + m * 16 + lr) * 32 + lg * 8];
#pragma unroll
    for (int n = 0; n < 4; n++)
      bw[n] = *(const bf16x8*)&sB[(wc * 64 + n * 16 + lr) * 32 + lg * 8];
#pragma unroll
    for (int m = 0; m < MR; m++)
#pragma unroll
      for (int n = 0; n < 4; n++)
        acc[m][n] = __builtin_amdgcn_mfma_f32_16x16x32_bf16(af[m], bw[n], acc[m][n], 0, 0, 0);
  }

#pragma unroll
  for (int m = 0; m < MR; m++) {
    const long rbase = row0 + wr * (BM/2) + m * 16 + lg * 4;
#pragma unroll
    for (int n = 0; n < 4; n++) {
      const long c = col0 + wc * 64 + n * 16 + lr;
      const float bv = (EPI == 3 && kz) ? 0.f : bias[c];
#pragma unroll
      for (int j = 0; j < 4; j++) {
        const long r = rbase + j;
        float val = acc[m][n][j] + bv;
        if (EPI == 0) {
          const int part = (int)(c >> 8);
          const int cc = (int)(c & 255);
          const int h = cc >> 5, hd = cc & 31;
          const int bi = (int)(r & 3);
          const int s = (int)(r >> 2);
          const int bh = bi * HH + h;
          if (part == 0) val *= 0.17677669529663687f;  // 1/sqrt(32)
          size_t idx;
          if (part == 2) {  // V transposed: [bh][hd][s]
            idx = (size_t)2 * (MM * DD) + ((size_t)bh * HDD + hd) * SS + s;
          } else {          // Q/K: [bh][s][hd]
            idx = (size_t)part * (MM * DD) + ((size_t)bh * SS + s) * HDD + hd;
          }
          ((short*)out)[idx] = (short)f2bf(val);
        } else if (EPI == 1) {
          ((float*)out)[(size_t)r * N + c] = val;
        } else if (EPI == 2) {
          ((short*)out)[(size_t)r * N + c] = (short)f2bf(fmaxf(val, 0.f));
        } else {
          float* op = kz ? (float*)out2 : (float*)out;
          op[(size_t)r * N + c] = val;
        }
      }
    }
  }
}

// ---------------- fused tanh-relu attention ----------------
// 32x32x16 MFMA, P fully in-register via cvt_pk + permlane32_swap.
// grid: (16 q-blocks of 128, 32 (b,h) pairs); block 256 = 4 waves x 32 q-rows.
// No LDS, no barriers.
__global__ __launch_bounds__(256)
void attn_kernel(const short* __restrict__ Qb, const short* __restrict__ Kb,
                 const short* __restrict__ VTb, short* __restrict__ Ob)
{
  const int tid = threadIdx.x;
  const int l = tid & 63, w = tid >> 6;
  const int q32 = l & 31, hf = l >> 5;        // lane col, lane half
  const int p = blockIdx.y;                   // b*8 + head
  const int q0 = blockIdx.x * 128 + w * 32;
  const size_t base = (size_t)p * SS * HDD;
  const short* Q  = Qb + base;
  const short* Kp = Kb + base;
  const short* VT = VTb + base;               // [d=32][s=2048]

  // Q frags (B operand): lane holds Q[q0+q32][kdim], slot k = hf*8 + j
  const short* qrow = &Q[(size_t)(q0 + q32) * HDD];
  const bf16x8 qf0 = *(const bf16x8*)&qrow[hf * 8];        // kdim 0..15
  const bf16x8 qf1 = *(const bf16x8*)&qrow[16 + hf * 8];   // kdim 16..31

  f32x16 acc = {};   // O^T[d][q]: col=q32, row d = (r&3)+8*(r>>2)+4*hf

  auto loadK = [&](int t0, bf16x8* kf) {
    const short* kr = &Kp[(size_t)(t0 + q32) * HDD];
    kf[0] = *(const bf16x8*)&kr[hf * 8];
    kf[1] = *(const bf16x8*)&kr[16 + hf * 8];
  };
  auto loadV = [&](int t0, bf16x8* vf) {
    const short* vr = &VT[(size_t)q32 * SS + t0];
    vf[0] = *(const bf16x8*)&vr[hf * 8];        // keys t0+0..15
    vf[1] = *(const bf16x8*)&vr[16 + hf * 8];   // keys t0+16..31
  };

  auto step = [&](const bf16x8* kf, const bf16x8* vf) {
    // scores D[key][q] over kdim=32: key = t0 + (r&3)+8*(r>>2)+4*hf, q = q32
    f32x16 z = {};
    f32x16 s = __builtin_amdgcn_mfma_f32_32x32x16_bf16(kf[0], qf0, z, 0, 0, 0);
    s = __builtin_amdgcn_mfma_f32_32x32x16_bf16(kf[1], qf1, s, 0, 0, 0);
    // relu(tanh(x)) = max(0, 1 - 2/(e^{2x}+1)); e^{2x} = 2^{x*2log2e}
    float pv[16];
#pragma unroll
    for (int r = 0; r < 16; r++) {
      const float e = exp2f(s[r] * 2.8853900817779268f);
      pv[r] = fmaxf(1.f - 2.f * __builtin_amdgcn_rcpf(e + 1.f), 0.f);
    }
    // pack to bf16 pairs: X[i] = pk(pv[2i], pv[2i+1])
    unsigned X0 = pk2(pv[0], pv[1]),  X1 = pk2(pv[2], pv[3]);
    unsigned X2 = pk2(pv[4], pv[5]),  X3 = pk2(pv[6], pv[7]);
    unsigned X4 = pk2(pv[8], pv[9]),  X5 = pk2(pv[10], pv[11]);
    unsigned X6 = pk2(pv[12], pv[13]), X7 = pk2(pv[14], pv[15]);
    // permlane32_swap: exchange upper-half lanes of arg0 with lower-half of arg1.
    uint2v r02 = __builtin_amdgcn_permlane32_swap(X0, X2, false, false);
    uint2v r13 = __builtin_amdgcn_permlane32_swap(X1, X3, false, false);
    uint2v r46 = __builtin_amdgcn_permlane32_swap(X4, X6, false, false);
    uint2v r57 = __builtin_amdgcn_permlane32_swap(X5, X7, false, false);
    // P frags (slot k holds key t0 + 16*frag + hf*8 + elem), matching V frags
    const uint4v f0 = { r02[0], r13[0], r02[1], r13[1] };
    const uint4v f1 = { r46[0], r57[0], r46[1], r57[1] };
    const bf16x8 pa0 = __builtin_bit_cast(bf16x8, f0);
    const bf16x8 pa1 = __builtin_bit_cast(bf16x8, f1);
    // O^T[d][q] += V^T[d][k] * P^T[k][q]
    acc = __builtin_amdgcn_mfma_f32_32x32x16_bf16(vf[0], pa0, acc, 0, 0, 0);
    acc = __builtin_amdgcn_mfma_f32_32x32x16_bf16(vf[1], pa1, acc, 0, 0, 0);
  };

  bf16x8 kA[2], vA[2], kB[2], vB[2];
  loadK(0, kA); loadV(0, vA);
  for (int t0 = 0; t0 < SS; t0 += 64) {
    loadK(t0 + 32, kB); loadV(t0 + 32, vB);
    step(kA, vA);
    const int tn = (t0 + 64 < SS) ? t0 + 64 : 0;
    loadK(tn, kA); loadV(tn, vA);
    step(kB, vB);
  }

  const int bi = p >> 3, hh = p & 7;
  short* orow = Ob + ((size_t)(q0 + q32) * BB + bi) * DD + hh * HDD;
#pragma unroll
  for (int r = 0; r < 16; r += 2) {
    const int d = (r & 3) + 8 * (r >> 2) + 4 * hf;
    *(unsigned*)&orow[d] = pk2(acc[r], acc[r + 1]);
  }
}

// ---------------- launch ----------------
extern "C" void kernel_launch(void* const* d_in, const int* in_sizes, int n_in,
                              void* d_out, int out_size, void* d_ws, size_t ws_size,
                              hipStream_t stream) {
  const float* features   = (const float*)d_in[0];
  const float* ln_g       = (const float*)d_in[1];
  const float* ln_b       = (const float*)d_in[2];
  const float* in_proj_w  = (const float*)d_in[3];
  const float* in_proj_b  = (const float*)d_in[4];
  const float* out_proj_w = (const float*)d_in[5];
  const float* out_proj_b = (const float*)d_in[6];
  const float* w1 = (const float*)d_in[7];
  const float* b1 = (const float*)d_in[8];
  const float* w2 = (const float*)d_in[9];
  const float* b2 = (const float*)d_in[10];

  char* ws = (char*)d_ws;
  const size_t MB = 1024 * 1024;
  float* lnx_f  = (float*)(ws + 0);        // 8MB  [0,8)   (dead after r1 LN; reused as ff partial)
  short* lnx_b  = (short*)(ws + 8 * MB);   // 4MB  [8,12)
  short* qkv    = (short*)(ws + 12 * MB);  // 12MB [12,24) q,k (per-bh rows), v^T
  short* attn_o = lnx_b;                   // reuse after QKV GEMM consumed lnx_b
  float* proj   = (float*)(ws + 12 * MB);  // 8MB  [12,20) reuse q/k after attention
  float* r1_f   = (float*)(ws + 20 * MB);  // 8MB  [20,28) reuse v
  short* r1_b   = (short*)(ws + 28 * MB);  // 4MB  [28,32)
  short* h1     = (short*)(ws + 32 * MB);  // 32MB [32,64)
  float* ffb    = proj;                    // reuse [12,20) after r1 LN
  float* ffp1   = lnx_f;                   // ff2 split-K partial 1, reuse [0,8)
  short* wqkv_b = (short*)(ws + 64 * MB);  // 768*256
  short* wout_b = wqkv_b + 768 * 256;      // 256*256
  short* w1_b   = wout_b + 256 * 256;      // 2048*256
  short* w2_b   = w1_b + 2048 * 256;       // 256*2048

  // 1) weight converts
  cvt_bf16<<<192, 256, 0, stream>>>(in_proj_w,  wqkv_b, 768 * 256 / 4);
  cvt_bf16<<<64,  256, 0, stream>>>(out_proj_w, wout_b, 256 * 256 / 4);
  cvt_bf16<<<512, 256, 0, stream>>>(w1, w1_b, 2048 * 256 / 4);
  cvt_bf16<<<512, 256, 0, stream>>>(w2, w2_b, 256 * 2048 / 4);

  // 2) ln_x = LN(features)
  ln_kernel<1, 1, 1><<<2048, 256, 0, stream>>>(features, nullptr, nullptr, ln_g, ln_b, lnx_f, lnx_b);

  // 3) qkv = ln_x @ in_proj_w^T + b  (scatter q/k per-(b,h), v transposed, q scaled)
  gemm_bt<0, 64><<<dim3(6, 128, 1), 256, 0, stream>>>(lnx_b, wqkv_b, in_proj_b, qkv, nullptr, 256, 768, 256);

  // 4) attention (relu(tanh(qk^T)) @ v), per (b,h), no LDS/barriers
  attn_kernel<<<dim3(16, 32), 256, 0, stream>>>(qkv, qkv + 2097152, qkv + 2 * 2097152, attn_o);

  // 5) proj = attn @ out_proj_w^T + b
  gemm_bt<1, 128><<<dim3(2, 64, 1), 256, 0, stream>>>(attn_o, wout_b, out_proj_b, proj, nullptr, 256, 256, 256);

  // 6) r1 = LN(ln_x + proj)
  ln_kernel<2, 1, 1><<<2048, 256, 0, stream>>>(lnx_f, proj, nullptr, ln_g, ln_b, r1_f, r1_b);

  // 7) h1 = relu(r1 @ w1^T + b1)
  gemm_bt<2, 128><<<dim3(16, 64, 1), 256, 0, stream>>>(r1_b, w1_b, b1, h1, nullptr, 256, 2048, 256);

  // 8) ff = h1 @ w2^T + b2  (split-K x2: partials in ffb, ffp1)
  gemm_bt<3, 128><<<dim3(2, 64, 2), 256, 0, stream>>>(h1, w2_b, b2, ffb, ffp1, 2048, 256, 1024);

  // 9) out = LN(r1 + ff0 + ff1)
  ln_kernel<3, 1, 0><<<2048, 256, 0, stream>>>(r1_f, ffb, ffp1, ln_g, ln_b, (float*)d_out, nullptr);
}

// Round 4
// 156.130 us; speedup vs baseline: 1.1692x; 1.1015x over previous
//
#include <hip/hip_runtime.h>
#include <hip/hip_bf16.h>

// Problem constants
#define SS 2048
#define BB 4
#define DD 256
#define HH 8
#define HDD 32
#define FFD 2048
#define MM (SS*BB)   // 8192 rows

typedef __attribute__((ext_vector_type(8))) __bf16 bf16x8;
typedef __attribute__((ext_vector_type(2))) __bf16 bf16x2;
typedef __attribute__((ext_vector_type(4))) short short4v;
typedef __attribute__((ext_vector_type(4))) float f32x4;
typedef __attribute__((ext_vector_type(16))) float f32x16;
typedef __attribute__((ext_vector_type(2))) unsigned uint2v;
typedef __attribute__((ext_vector_type(4))) unsigned uint4v;
typedef __attribute__((ext_vector_type(2))) float f32x2;

__device__ __forceinline__ unsigned short f2bf(float f) {
  union { float f; unsigned u; } v; v.f = f;
  unsigned r = v.u + 0x7fffu + ((v.u >> 16) & 1u);
  return (unsigned short)(r >> 16);
}

__device__ __forceinline__ unsigned pk2(float a, float b) {
  bf16x2 t; t[0] = (__bf16)a; t[1] = (__bf16)b;
  return __builtin_bit_cast(unsigned, t);
}

__device__ __forceinline__ void gload16(const void* g, void* l) {
  __builtin_amdgcn_global_load_lds(
      (const __attribute__((address_space(1))) void*)g,
      (__attribute__((address_space(3))) void*)l, 16, 0, 0);
}

// ---------------- weight convert f32 -> bf16 ----------------
__global__ __launch_bounds__(256)
void cvt_bf16(const float* __restrict__ in, short* __restrict__ out, int n4) {
  int i = blockIdx.x * 256 + threadIdx.x;
  if (i < n4) {
    float4 x = ((const float4*)in)[i];
    short4v o = { (short)f2bf(x.x), (short)f2bf(x.y), (short)f2bf(x.z), (short)f2bf(x.w) };
    ((short4v*)out)[i] = o;
  }
}

// ---------------- merge two f32 partials -> bf16 ----------------
__global__ __launch_bounds__(256)
void merge_bf16(const float* __restrict__ a, const float* __restrict__ b,
                short* __restrict__ out, int n4) {
  int i = blockIdx.x * 256 + threadIdx.x;
  if (i < n4) {
    float4 x = ((const float4*)a)[i];
    float4 y = ((const float4*)b)[i];
    short4v o = { (short)f2bf(x.x + y.x), (short)f2bf(x.y + y.y),
                  (short)f2bf(x.z + y.z), (short)f2bf(x.w + y.w) };
    ((short4v*)out)[i] = o;
  }
}

// ---------------- LayerNorm over D=256, one wave per row ----------------
template<int NIN, int WF, int WBF>
__global__ __launch_bounds__(256)
void ln_kernel(const float* __restrict__ xa, const float* __restrict__ xb,
               const float* __restrict__ xc,
               const float* __restrict__ gam, const float* __restrict__ bet,
               float* __restrict__ outf, short* __restrict__ outb)
{
  const int w = threadIdx.x >> 6, l = threadIdx.x & 63;
  const size_t row = (size_t)blockIdx.x * 4 + w;
  float4 x = *(const float4*)&xa[row * 256 + l * 4];
  if (NIN >= 2) {
    const float4 y = *(const float4*)&xb[row * 256 + l * 4];
    x.x += y.x; x.y += y.y; x.z += y.z; x.w += y.w;
  }
  if (NIN >= 3) {
    const float4 y = *(const float4*)&xc[row * 256 + l * 4];
    x.x += y.x; x.y += y.y; x.z += y.z; x.w += y.w;
  }
  float sum = x.x + x.y + x.z + x.w;
  float sq  = x.x*x.x + x.y*x.y + x.z*x.z + x.w*x.w;
#pragma unroll
  for (int off = 32; off > 0; off >>= 1) {
    sum += __shfl_xor(sum, off);
    sq  += __shfl_xor(sq, off);
  }
  const float mu = sum * (1.f / 256.f);
  const float rs = rsqrtf(sq * (1.f / 256.f) - mu * mu + 1e-5f);
  const float4 g4 = *(const float4*)&gam[l * 4];
  const float4 b4 = *(const float4*)&bet[l * 4];
  const float y0 = (x.x - mu) * rs * g4.x + b4.x;
  const float y1 = (x.y - mu) * rs * g4.y + b4.y;
  const float y2 = (x.z - mu) * rs * g4.z + b4.z;
  const float y3 = (x.w - mu) * rs * g4.w + b4.w;
  if (WF) {
    float4 o; o.x = y0; o.y = y1; o.z = y2; o.w = y3;
    *(float4*)&outf[row * 256 + l * 4] = o;
  }
  if (WBF) {
    short4v o = { (short)f2bf(y0), (short)f2bf(y1), (short)f2bf(y2), (short)f2bf(y3) };
    *(short4v*)&outb[row * 256 + l * 4] = o;
  }
}

// ---------------- bf16 GEMM, C = A(MxK) * W(NxK)^T + bias, BMx128 tile ----------------
// EPI 0: qkv scatter (q scaled by 2log2e/sqrt(hd), v transposed), bf16 out
// EPI 1: f32 out (out_proj)
// EPI 2: relu, bf16 out (ff1)
// EPI 3: f32 out, split-K via blockIdx.z (partial 1 -> out2, no bias)
template<int EPI, int BM>
__global__ __launch_bounds__(256)
void gemm_bt(const short* __restrict__ A, const short* __restrict__ W,
             const float* __restrict__ bias, void* __restrict__ out,
             void* __restrict__ out2, int K, int N, int Ksub)
{
  __shared__ short sA[BM * 32];
  __shared__ short sB[128 * 32];
  const int tid = threadIdx.x;
  const int l  = tid & 63;
  const int w  = tid >> 6;
  const int wr = w >> 1, wc = w & 1;
  const int lr = l & 15, lg = l >> 4;
  const long row0 = (long)blockIdx.y * BM;
  const long col0 = (long)blockIdx.x * 128;
  const int kz = blockIdx.z;
  const int kbeg = kz * Ksub;
  const int ldsw = (tid & ~63) * 16;   // wave-uniform LDS byte base
  constexpr int MR = BM / 32;          // m-frags per wave
  f32x4 acc[MR][4] = {};

  for (int k0 = kbeg; k0 < kbeg + Ksub; k0 += 32) {
    __syncthreads();
#pragma unroll
    for (int i = 0; i < BM / 64; i++) {
      const int o = (i * 256 + tid) * 16;     // byte offset in A tile
      const int r = o >> 6, cb = o & 63;      // row, byte-in-row (32 bf16 = 64B rows)
      gload16((const char*)A + ((row0 + r) * K + k0) * 2 + cb,
              (char*)sA + i * 4096 + ldsw);
    }
#pragma unroll
    for (int i = 0; i < 2; i++) {
      const int o = (i * 256 + tid) * 16;
      const int r = o >> 6, cb = o & 63;
      gload16((const char*)W + ((col0 + r) * K + k0) * 2 + cb,
              (char*)sB + i * 4096 + ldsw);
    }
    __syncthreads();
    bf16x8 af[MR], bw[4];
#pragma unroll
    for (int m = 0; m < MR; m++)
      af[m] = *(const bf16x8*)&sA[(wr * (BM/2) + m * 16 + lr) * 32 + lg * 8];
#pragma unroll
    for (int n = 0; n < 4; n++)
      bw[n] = *(const bf16x8*)&sB[(wc * 64 + n * 16 + lr) * 32 + lg * 8];
#pragma unroll
    for (int m = 0; m < MR; m++)
#pragma unroll
      for (int n = 0; n < 4; n++)
        acc[m][n] = __builtin_amdgcn_mfma_f32_16x16x32_bf16(af[m], bw[n], acc[m][n], 0, 0, 0);
  }

#pragma unroll
  for (int m = 0; m < MR; m++) {
    const long rbase = row0 + wr * (BM/2) + m * 16 + lg * 4;
#pragma unroll
    for (int n = 0; n < 4; n++) {
      const long c = col0 + wc * 64 + n * 16 + lr;
      const float bv = (EPI == 3 && kz) ? 0.f : bias[c];
#pragma unroll
      for (int j = 0; j < 4; j++) {
        const long r = rbase + j;
        float val = acc[m][n][j] + bv;
        if (EPI == 0) {
          const int part = (int)(c >> 8);
          const int cc = (int)(c & 255);
          const int h = cc >> 5, hd = cc & 31;
          const int bi = (int)(r & 3);
          const int s = (int)(r >> 2);
          const int bh = bi * HH + h;
          // q scale: (1/sqrt(32)) * 2*log2(e)  (activation uses exp2 directly)
          if (part == 0) val *= 0.51006972771029396f;
          size_t idx;
          if (part == 2) {  // V transposed: [bh][hd][s]
            idx = (size_t)2 * (MM * DD) + ((size_t)bh * HDD + hd) * SS + s;
          } else {          // Q/K: [bh][s][hd]
            idx = (size_t)part * (MM * DD) + ((size_t)bh * SS + s) * HDD + hd;
          }
          ((short*)out)[idx] = (short)f2bf(val);
        } else if (EPI == 1) {
          ((float*)out)[(size_t)r * N + c] = val;
        } else if (EPI == 2) {
          ((short*)out)[(size_t)r * N + c] = (short)f2bf(fmaxf(val, 0.f));
        } else {
          float* op = kz ? (float*)out2 : (float*)out;
          op[(size_t)r * N + c] = val;
        }
      }
    }
  }
}

// ---------------- fused tanh-relu attention ----------------
// 32x32x16 MFMA, P fully in-register via cvt_pk + permlane32_swap.
// grid: (16 q-blocks of 128, 32 (b,h) pairs, 2 key-halves); 4 waves x 32 q-rows.
// Split-K partials in f32. Dual accumulators break the PV dependency chain.
__global__ __launch_bounds__(256, 4)
void attn_kernel(const short* __restrict__ Qb, const short* __restrict__ Kb,
                 const short* __restrict__ VTb,
                 float* __restrict__ O0, float* __restrict__ O1)
{
  const int tid = threadIdx.x;
  const int l = tid & 63, w = tid >> 6;
  const int q32 = l & 31, hf = l >> 5;        // lane col, lane half
  const int p = blockIdx.y;                   // b*8 + head
  const int q0 = blockIdx.x * 128 + w * 32;
  const int kz = blockIdx.z;
  const int kbeg = kz * (SS / 2);
  const size_t base = (size_t)p * SS * HDD;
  const short* Q  = Qb + base;
  const short* Kp = Kb + base;
  const short* VT = VTb + base;               // [d=32][s=2048]

  // Q frags (B operand): lane holds Q[q0+q32][kdim], slot k = hf*8 + j
  const short* qrow = &Q[(size_t)(q0 + q32) * HDD];
  const bf16x8 qf0 = *(const bf16x8*)&qrow[hf * 8];        // kdim 0..15
  const bf16x8 qf1 = *(const bf16x8*)&qrow[16 + hf * 8];   // kdim 16..31

  const f32x16 fzero = {};
  f32x16 accA = {}, accB = {};   // O^T[d][q]: col=q32, row d = (r&3)+8*(r>>2)+4*hf

  auto loadK = [&](int t0, bf16x8* kf) {
    const short* kr = &Kp[(size_t)(t0 + q32) * HDD];
    kf[0] = *(const bf16x8*)&kr[hf * 8];
    kf[1] = *(const bf16x8*)&kr[16 + hf * 8];
  };
  auto loadV = [&](int t0, bf16x8* vf) {
    const short* vr = &VT[(size_t)q32 * SS + t0];
    vf[0] = *(const bf16x8*)&vr[hf * 8];        // keys t0+0..15
    vf[1] = *(const bf16x8*)&vr[16 + hf * 8];   // keys t0+16..31
  };

  auto step = [&](const bf16x8* kf, const bf16x8* vf, f32x16& acc) {
    // scores D[key][q] over kdim=32 (pre-scaled by 2log2e/sqrt(32))
    f32x16 s = __builtin_amdgcn_mfma_f32_32x32x16_bf16(kf[0], qf0, fzero, 0, 0, 0);
    s = __builtin_amdgcn_mfma_f32_32x32x16_bf16(kf[1], qf1, s, 0, 0, 0);
    // relu(tanh(x)) = max(0, 1 - 2/(exp2(s)+1))
    float pv[16];
#pragma unroll
    for (int r = 0; r < 16; r++) {
      const float e = __builtin_amdgcn_exp2f(s[r]);
      pv[r] = fmaxf(1.f - 2.f * __builtin_amdgcn_rcpf(e + 1.f), 0.f);
    }
    unsigned X0 = pk2(pv[0], pv[1]),   X1 = pk2(pv[2], pv[3]);
    unsigned X2 = pk2(pv[4], pv[5]),   X3 = pk2(pv[6], pv[7]);
    unsigned X4 = pk2(pv[8], pv[9]),   X5 = pk2(pv[10], pv[11]);
    unsigned X6 = pk2(pv[12], pv[13]), X7 = pk2(pv[14], pv[15]);
    uint2v r02 = __builtin_amdgcn_permlane32_swap(X0, X2, false, false);
    uint2v r13 = __builtin_amdgcn_permlane32_swap(X1, X3, false, false);
    uint2v r46 = __builtin_amdgcn_permlane32_swap(X4, X6, false, false);
    uint2v r57 = __builtin_amdgcn_permlane32_swap(X5, X7, false, false);
    const uint4v f0 = { r02[0], r13[0], r02[1], r13[1] };
    const uint4v f1 = { r46[0], r57[0], r46[1], r57[1] };
    const bf16x8 pa0 = __builtin_bit_cast(bf16x8, f0);
    const bf16x8 pa1 = __builtin_bit_cast(bf16x8, f1);
    // O^T[d][q] += V^T[d][k] * P^T[k][q]
    acc = __builtin_amdgcn_mfma_f32_32x32x16_bf16(vf[0], pa0, acc, 0, 0, 0);
    acc = __builtin_amdgcn_mfma_f32_32x32x16_bf16(vf[1], pa1, acc, 0, 0, 0);
  };

  bf16x8 kA[2], vA[2], kB[2], vB[2];
  loadK(kbeg, kA); loadV(kbeg, vA);
  for (int t0 = kbeg; t0 < kbeg + SS / 2; t0 += 64) {
    loadK(t0 + 32, kB); loadV(t0 + 32, vB);
    step(kA, vA, accA);
    const int tn = (t0 + 64 < kbeg + SS / 2) ? t0 + 64 : kbeg;
    loadK(tn, kA); loadV(tn, vA);
    step(kB, vB, accB);
  }

  const int bi = p >> 3, hh = p & 7;
  float* Op = kz ? O1 : O0;
  float* orow = Op + ((size_t)(q0 + q32) * BB + bi) * DD + hh * HDD;
#pragma unroll
  for (int r = 0; r < 16; r += 2) {
    const int d = (r & 3) + 8 * (r >> 2) + 4 * hf;
    f32x2 o2 = { accA[r] + accB[r], accA[r + 1] + accB[r + 1] };
    *(f32x2*)&orow[d] = o2;
  }
}

// ---------------- launch ----------------
extern "C" void kernel_launch(void* const* d_in, const int* in_sizes, int n_in,
                              void* d_out, int out_size, void* d_ws, size_t ws_size,
                              hipStream_t stream) {
  const float* features   = (const float*)d_in[0];
  const float* ln_g       = (const float*)d_in[1];
  const float* ln_b       = (const float*)d_in[2];
  const float* in_proj_w  = (const float*)d_in[3];
  const float* in_proj_b  = (const float*)d_in[4];
  const float* out_proj_w = (const float*)d_in[5];
  const float* out_proj_b = (const float*)d_in[6];
  const float* w1 = (const float*)d_in[7];
  const float* b1 = (const float*)d_in[8];
  const float* w2 = (const float*)d_in[9];
  const float* b2 = (const float*)d_in[10];

  char* ws = (char*)d_ws;
  const size_t MB = 1024 * 1024;
  float* lnx_f  = (float*)(ws + 0);        // 8MB  [0,8)   (dead after r1 LN; reused as ff partial)
  short* lnx_b  = (short*)(ws + 8 * MB);   // 4MB  [8,12)
  short* qkv    = (short*)(ws + 12 * MB);  // 12MB [12,24) q,k (per-bh rows), v^T
  short* attn_o = lnx_b;                   // reuse after QKV GEMM consumed lnx_b
  float* proj   = (float*)(ws + 12 * MB);  // 8MB  [12,20) reuse q/k after attention
  float* r1_f   = (float*)(ws + 20 * MB);  // 8MB  [20,28) reuse v
  short* r1_b   = (short*)(ws + 28 * MB);  // 4MB  [28,32)
  short* h1     = (short*)(ws + 32 * MB);  // 32MB [32,64) (ff1 out; also attn partials before)
  float* aO0    = (float*)(ws + 32 * MB);  // 8MB  [32,40) attn split-K partial 0
  float* aO1    = (float*)(ws + 40 * MB);  // 8MB  [40,48) attn split-K partial 1
  float* ffb    = proj;                    // reuse [12,20) after r1 LN
  float* ffp1   = lnx_f;                   // ff2 split-K partial 1, reuse [0,8)
  short* wqkv_b = (short*)(ws + 64 * MB);  // 768*256
  short* wout_b = wqkv_b + 768 * 256;      // 256*256
  short* w1_b   = wout_b + 256 * 256;      // 2048*256
  short* w2_b   = w1_b + 2048 * 256;       // 256*2048

  // 1) weight converts
  cvt_bf16<<<192, 256, 0, stream>>>(in_proj_w,  wqkv_b, 768 * 256 / 4);
  cvt_bf16<<<64,  256, 0, stream>>>(out_proj_w, wout_b, 256 * 256 / 4);
  cvt_bf16<<<512, 256, 0, stream>>>(w1, w1_b, 2048 * 256 / 4);
  cvt_bf16<<<512, 256, 0, stream>>>(w2, w2_b, 256 * 2048 / 4);

  // 2) ln_x = LN(features)
  ln_kernel<1, 1, 1><<<2048, 256, 0, stream>>>(features, nullptr, nullptr, ln_g, ln_b, lnx_f, lnx_b);

  // 3) qkv = ln_x @ in_proj_w^T + b  (scatter q/k per-(b,h), v transposed, q scaled)
  gemm_bt<0, 64><<<dim3(6, 128, 1), 256, 0, stream>>>(lnx_b, wqkv_b, in_proj_b, qkv, nullptr, 256, 768, 256);

  // 4) attention (relu(tanh(qk^T)) @ v), split-K x2, f32 partials
  attn_kernel<<<dim3(16, 32, 2), 256, 0, stream>>>(qkv, qkv + 2097152, qkv + 2 * 2097152, aO0, aO1);
  merge_bf16<<<2048, 256, 0, stream>>>(aO0, aO1, attn_o, MM * DD / 4);

  // 5) proj = attn @ out_proj_w^T + b
  gemm_bt<1, 64><<<dim3(2, 128, 1), 256, 0, stream>>>(attn_o, wout_b, out_proj_b, proj, nullptr, 256, 256, 256);

  // 6) r1 = LN(ln_x + proj)
  ln_kernel<2, 1, 1><<<2048, 256, 0, stream>>>(lnx_f, proj, nullptr, ln_g, ln_b, r1_f, r1_b);

  // 7) h1 = relu(r1 @ w1^T + b1)
  gemm_bt<2, 128><<<dim3(16, 64, 1), 256, 0, stream>>>(r1_b, w1_b, b1, h1, nullptr, 256, 2048, 256);

  // 8) ff = h1 @ w2^T + b2  (split-K x2: partials in ffb, ffp1)
  gemm_bt<3, 128><<<dim3(2, 64, 2), 256, 0, stream>>>(h1, w2_b, b2, ffb, ffp1, 2048, 256, 1024);

  // 9) out = LN(r1 + ff0 + ff1)
  ln_kernel<3, 1, 0><<<2048, 256, 0, stream>>>(r1_f, ffb, ffp1, ln_g, ln_b, (float*)d_out, nullptr);
}

// Round 5
// 152.288 us; speedup vs baseline: 1.1987x; 1.0252x over previous
//
#include <hip/hip_runtime.h>
#include <hip/hip_bf16.h>

// Problem constants
#define SS 2048
#define BB 4
#define DD 256
#define HH 8
#define HDD 32
#define FFD 2048
#define MM (SS*BB)   // 8192 rows

typedef __attribute__((ext_vector_type(8))) __bf16 bf16x8;
typedef __attribute__((ext_vector_type(2))) __bf16 bf16x2;
typedef __attribute__((ext_vector_type(4))) short short4v;
typedef __attribute__((ext_vector_type(4))) float f32x4;
typedef __attribute__((ext_vector_type(16))) float f32x16;
typedef __attribute__((ext_vector_type(2))) unsigned uint2v;
typedef __attribute__((ext_vector_type(4))) unsigned uint4v;

__device__ __forceinline__ unsigned short f2bf(float f) {
  union { float f; unsigned u; } v; v.f = f;
  unsigned r = v.u + 0x7fffu + ((v.u >> 16) & 1u);
  return (unsigned short)(r >> 16);
}

__device__ __forceinline__ unsigned pk2(float a, float b) {
  bf16x2 t; t[0] = (__bf16)a; t[1] = (__bf16)b;
  return __builtin_bit_cast(unsigned, t);
}

__device__ __forceinline__ void gload16(const void* g, void* l) {
  __builtin_amdgcn_global_load_lds(
      (const __attribute__((address_space(1))) void*)g,
      (__attribute__((address_space(3))) void*)l, 16, 0, 0);
}

// ---------------- all weight converts f32 -> bf16, one kernel ----------------
__global__ __launch_bounds__(256)
void cvt_all(const float* __restrict__ a, const float* __restrict__ b,
             const float* __restrict__ c, const float* __restrict__ d,
             short* __restrict__ oa, short* __restrict__ ob,
             short* __restrict__ oc, short* __restrict__ od) {
  const int which = blockIdx.y;
  const float* in; short* out; int n4;
  if (which == 0)      { in = a; out = oa; n4 = 768 * 256 / 4; }
  else if (which == 1) { in = b; out = ob; n4 = 256 * 256 / 4; }
  else if (which == 2) { in = c; out = oc; n4 = 2048 * 256 / 4; }
  else                 { in = d; out = od; n4 = 2048 * 256 / 4; }
  const int i = blockIdx.x * 256 + threadIdx.x;
  if (i < n4) {
    float4 x = ((const float4*)in)[i];
    short4v o = { (short)f2bf(x.x), (short)f2bf(x.y), (short)f2bf(x.z), (short)f2bf(x.w) };
    ((short4v*)out)[i] = o;
  }
}

// ---------------- LayerNorm over D=256, one wave per row ----------------
template<int NIN, int WF, int WBF>
__global__ __launch_bounds__(256)
void ln_kernel(const float* __restrict__ xa, const float* __restrict__ xb,
               const float* __restrict__ xc,
               const float* __restrict__ gam, const float* __restrict__ bet,
               float* __restrict__ outf, short* __restrict__ outb)
{
  const int w = threadIdx.x >> 6, l = threadIdx.x & 63;
  const size_t row = (size_t)blockIdx.x * 4 + w;
  float4 x = *(const float4*)&xa[row * 256 + l * 4];
  if (NIN >= 2) {
    const float4 y = *(const float4*)&xb[row * 256 + l * 4];
    x.x += y.x; x.y += y.y; x.z += y.z; x.w += y.w;
  }
  if (NIN >= 3) {
    const float4 y = *(const float4*)&xc[row * 256 + l * 4];
    x.x += y.x; x.y += y.y; x.z += y.z; x.w += y.w;
  }
  float sum = x.x + x.y + x.z + x.w;
  float sq  = x.x*x.x + x.y*x.y + x.z*x.z + x.w*x.w;
#pragma unroll
  for (int off = 32; off > 0; off >>= 1) {
    sum += __shfl_xor(sum, off);
    sq  += __shfl_xor(sq, off);
  }
  const float mu = sum * (1.f / 256.f);
  const float rs = rsqrtf(sq * (1.f / 256.f) - mu * mu + 1e-5f);
  const float4 g4 = *(const float4*)&gam[l * 4];
  const float4 b4 = *(const float4*)&bet[l * 4];
  const float y0 = (x.x - mu) * rs * g4.x + b4.x;
  const float y1 = (x.y - mu) * rs * g4.y + b4.y;
  const float y2 = (x.z - mu) * rs * g4.z + b4.z;
  const float y3 = (x.w - mu) * rs * g4.w + b4.w;
  if (WF) {
    float4 o; o.x = y0; o.y = y1; o.z = y2; o.w = y3;
    *(float4*)&outf[row * 256 + l * 4] = o;
  }
  if (WBF) {
    short4v o = { (short)f2bf(y0), (short)f2bf(y1), (short)f2bf(y2), (short)f2bf(y3) };
    *(short4v*)&outb[row * 256 + l * 4] = o;
  }
}

// ---------------- bf16 GEMM, C = A(MxK) * W(NxK)^T + bias, BMxBN tile ----------------
// Double-buffered LDS, 2-phase: stage(t+1) issued before compute(t); single
// __syncthreads per iter so the vmcnt(0) drain lands after the MFMAs.
// KW != 0: W's K-stride (stacked-partial trick: W column index wraps mod KW).
// EPI 0: qkv scatter (q scaled by 2log2e/sqrt(hd), v transposed), bf16 out
// EPI 1: f32 out (out_proj)
// EPI 2: relu, bf16 out (ff1)
// EPI 3: f32 out, split-K via blockIdx.z (partial 1 -> out2, no bias)
template<int EPI, int BM, int BN, int KW>
__global__ __launch_bounds__(256)
void gemm_bt(const short* __restrict__ A, const short* __restrict__ W,
             const float* __restrict__ bias, void* __restrict__ out,
             void* __restrict__ out2, int K, int N, int Ksub)
{
  __shared__ short sA[2][BM * 32];
  __shared__ short sB[2][BN * 32];
  const int tid = threadIdx.x;
  const int l  = tid & 63;
  const int w  = tid >> 6;
  const int wr = w >> 1, wc = w & 1;
  const int lr = l & 15, lg = l >> 4;
  const long row0 = (long)blockIdx.y * BM;
  const long col0 = (long)blockIdx.x * BN;
  const int kz = blockIdx.z;
  const int kbeg = kz * Ksub;
  const int ldsw = (tid & ~63) * 16;   // wave-uniform LDS byte base
  constexpr int MR = BM / 32, NR = BN / 32;
  f32x4 acc[MR][NR] = {};
  const int nt = Ksub / 32;

  auto stage = [&](int buf, int k0) {
#pragma unroll
    for (int i = 0; i < BM / 64; i++) {
      const int o = (i * 256 + tid) * 16;     // byte offset in A tile
      const int r = o >> 6, cb = o & 63;      // row, byte-in-row (32 bf16 = 64B)
      gload16((const char*)A + ((row0 + r) * (long)K + k0) * 2 + cb,
              (char*)sA[buf] + i * 4096 + ldsw);
    }
    const long wstride = KW ? KW : K;
    const long wk = KW ? (k0 & (KW - 1)) : k0;
#pragma unroll
    for (int i = 0; i < BN / 64; i++) {
      const int o = (i * 256 + tid) * 16;
      const int r = o >> 6, cb = o & 63;
      gload16((const char*)W + ((col0 + r) * wstride + wk) * 2 + cb,
              (char*)sB[buf] + i * 4096 + ldsw);
    }
  };

  stage(0, kbeg);
  __syncthreads();
  int cur = 0;
  for (int t = 0; t < nt; t++) {
    if (t + 1 < nt) stage(cur ^ 1, kbeg + (t + 1) * 32);
    bf16x8 af[MR], bw[NR];
#pragma unroll
    for (int m = 0; m < MR; m++)
      af[m] = *(const bf16x8*)&sA[cur][(wr * (BM/2) + m * 16 + lr) * 32 + lg * 8];
#pragma unroll
    for (int n = 0; n < NR; n++)
      bw[n] = *(const bf16x8*)&sB[cur][(wc * (BN/2) + n * 16 + lr) * 32 + lg * 8];
#pragma unroll
    for (int m = 0; m < MR; m++)
#pragma unroll
      for (int n = 0; n < NR; n++)
        acc[m][n] = __builtin_amdgcn_mfma_f32_16x16x32_bf16(af[m], bw[n], acc[m][n], 0, 0, 0);
    __syncthreads();
    cur ^= 1;
  }

#pragma unroll
  for (int m = 0; m < MR; m++) {
    const long rbase = row0 + wr * (BM/2) + m * 16 + lg * 4;
#pragma unroll
    for (int n = 0; n < NR; n++) {
      const long c = col0 + wc * (BN/2) + n * 16 + lr;
      const float bv = (EPI == 3 && kz) ? 0.f : bias[c];
#pragma unroll
      for (int j = 0; j < 4; j++) {
        const long r = rbase + j;
        float val = acc[m][n][j] + bv;
        if (EPI == 0) {
          const int part = (int)(c >> 8);
          const int cc = (int)(c & 255);
          const int h = cc >> 5, hd = cc & 31;
          const int bi = (int)(r & 3);
          const int s = (int)(r >> 2);
          const int bh = bi * HH + h;
          // q scale: (1/sqrt(32)) * 2*log2(e)  (activation uses exp2 directly)
          if (part == 0) val *= 0.51006972771029396f;
          size_t idx;
          if (part == 2) {  // V transposed: [bh][hd][s]
            idx = (size_t)2 * (MM * DD) + ((size_t)bh * HDD + hd) * SS + s;
          } else {          // Q/K: [bh][s][hd]
            idx = (size_t)part * (MM * DD) + ((size_t)bh * SS + s) * HDD + hd;
          }
          ((short*)out)[idx] = (short)f2bf(val);
        } else if (EPI == 1) {
          ((float*)out)[(size_t)r * N + c] = val;
        } else if (EPI == 2) {
          ((short*)out)[(size_t)r * N + c] = (short)f2bf(fmaxf(val, 0.f));
        } else {
          float* op = kz ? (float*)out2 : (float*)out;
          op[(size_t)r * N + c] = val;
        }
      }
    }
  }
}

// ---------------- fused tanh-relu attention ----------------
// 32x32x16 MFMA, P fully in-register via cvt_pk + permlane32_swap.
// grid: (16 q-blocks of 128, 32 (b,h) pairs, 4 key-quarters); 4 waves x 32 q.
// bf16 partials written to stacked A' [row][kz*256 + h*32 + d]; the out_proj
// GEMM sums the partials via K=1024 with W wrapping mod 256 (linearity).
__global__ __launch_bounds__(256, 4)
void attn_kernel(const short* __restrict__ Qb, const short* __restrict__ Kb,
                 const short* __restrict__ VTb, short* __restrict__ Aout)
{
  const int tid = threadIdx.x;
  const int l = tid & 63, w = tid >> 6;
  const int q32 = l & 31, hf = l >> 5;        // lane col, lane half
  const int p = blockIdx.y;                   // b*8 + head
  const int q0 = blockIdx.x * 128 + w * 32;
  const int kz = blockIdx.z;
  const int kbeg = kz * (SS / 4);
  const int kend = kbeg + SS / 4;
  const size_t base = (size_t)p * SS * HDD;
  const short* Q  = Qb + base;
  const short* Kp = Kb + base;
  const short* VT = VTb + base;               // [d=32][s=2048]

  // Q frags (B operand): lane holds Q[q0+q32][kdim], slot k = hf*8 + j
  const short* qrow = &Q[(size_t)(q0 + q32) * HDD];
  const bf16x8 qf0 = *(const bf16x8*)&qrow[hf * 8];        // kdim 0..15
  const bf16x8 qf1 = *(const bf16x8*)&qrow[16 + hf * 8];   // kdim 16..31

  const f32x16 fzero = {};
  f32x16 accA = {}, accB = {};   // O^T[d][q]: col=q32, row d = (r&3)+8*(r>>2)+4*hf

  auto loadK = [&](int t0, bf16x8* kf) {
    const short* kr = &Kp[(size_t)(t0 + q32) * HDD];
    kf[0] = *(const bf16x8*)&kr[hf * 8];
    kf[1] = *(const bf16x8*)&kr[16 + hf * 8];
  };
  auto loadV = [&](int t0, bf16x8* vf) {
    const short* vr = &VT[(size_t)q32 * SS + t0];
    vf[0] = *(const bf16x8*)&vr[hf * 8];        // keys t0+0..15
    vf[1] = *(const bf16x8*)&vr[16 + hf * 8];   // keys t0+16..31
  };

  auto step = [&](const bf16x8* kf, const bf16x8* vf, f32x16& acc) {
    // scores D[key][q] over kdim=32 (pre-scaled by 2log2e/sqrt(32))
    f32x16 s = __builtin_amdgcn_mfma_f32_32x32x16_bf16(kf[0], qf0, fzero, 0, 0, 0);
    s = __builtin_amdgcn_mfma_f32_32x32x16_bf16(kf[1], qf1, s, 0, 0, 0);
    // relu(tanh(x)) = max(0, 1 - 2/(exp2(s)+1))
    float pv[16];
#pragma unroll
    for (int r = 0; r < 16; r++) {
      const float e = __builtin_amdgcn_exp2f(s[r]);
      pv[r] = fmaxf(1.f - 2.f * __builtin_amdgcn_rcpf(e + 1.f), 0.f);
    }
    unsigned X0 = pk2(pv[0], pv[1]),   X1 = pk2(pv[2], pv[3]);
    unsigned X2 = pk2(pv[4], pv[5]),   X3 = pk2(pv[6], pv[7]);
    unsigned X4 = pk2(pv[8], pv[9]),   X5 = pk2(pv[10], pv[11]);
    unsigned X6 = pk2(pv[12], pv[13]), X7 = pk2(pv[14], pv[15]);
    uint2v r02 = __builtin_amdgcn_permlane32_swap(X0, X2, false, false);
    uint2v r13 = __builtin_amdgcn_permlane32_swap(X1, X3, false, false);
    uint2v r46 = __builtin_amdgcn_permlane32_swap(X4, X6, false, false);
    uint2v r57 = __builtin_amdgcn_permlane32_swap(X5, X7, false, false);
    const uint4v f0 = { r02[0], r13[0], r02[1], r13[1] };
    const uint4v f1 = { r46[0], r57[0], r46[1], r57[1] };
    const bf16x8 pa0 = __builtin_bit_cast(bf16x8, f0);
    const bf16x8 pa1 = __builtin_bit_cast(bf16x8, f1);
    // O^T[d][q] += V^T[d][k] * P^T[k][q]
    acc = __builtin_amdgcn_mfma_f32_32x32x16_bf16(vf[0], pa0, acc, 0, 0, 0);
    acc = __builtin_amdgcn_mfma_f32_32x32x16_bf16(vf[1], pa1, acc, 0, 0, 0);
  };

  bf16x8 kA[2], vA[2], kB[2], vB[2];
  loadK(kbeg, kA); loadV(kbeg, vA);
  for (int t0 = kbeg; t0 < kend; t0 += 64) {
    loadK(t0 + 32, kB); loadV(t0 + 32, vB);
    step(kA, vA, accA);
    const int tn = (t0 + 64 < kend) ? t0 + 64 : kbeg;
    loadK(tn, kA); loadV(tn, vA);
    step(kB, vB, accB);
  }

  const int bi = p >> 3, hh = p & 7;
  // A' row = s*BB+bi, K-stride 1024, partial kz at cols [kz*256, kz*256+256)
  short* orow = Aout + ((size_t)(q0 + q32) * BB + bi) * (4 * DD) + kz * DD + hh * HDD;
#pragma unroll
  for (int r = 0; r < 16; r += 2) {
    const int d = (r & 3) + 8 * (r >> 2) + 4 * hf;
    *(unsigned*)&orow[d] = pk2(accA[r] + accB[r], accA[r + 1] + accB[r + 1]);
  }
}

// ---------------- launch ----------------
extern "C" void kernel_launch(void* const* d_in, const int* in_sizes, int n_in,
                              void* d_out, int out_size, void* d_ws, size_t ws_size,
                              hipStream_t stream) {
  const float* features   = (const float*)d_in[0];
  const float* ln_g       = (const float*)d_in[1];
  const float* ln_b       = (const float*)d_in[2];
  const float* in_proj_w  = (const float*)d_in[3];
  const float* in_proj_b  = (const float*)d_in[4];
  const float* out_proj_w = (const float*)d_in[5];
  const float* out_proj_b = (const float*)d_in[6];
  const float* w1 = (const float*)d_in[7];
  const float* b1 = (const float*)d_in[8];
  const float* w2 = (const float*)d_in[9];
  const float* b2 = (const float*)d_in[10];

  char* ws = (char*)d_ws;
  const size_t MB = 1024 * 1024;
  // [0,8)   lnx_f            -> ffp1 (after r1 LN)
  // [8,12)  lnx_b
  // [12,24) qkv (q,k,vT)     -> [12,20) proj -> ffb ; [20,24) r1_b
  // [24,40) A' (attn stacked partials, bf16 8192x1024) -> [24,32) r1_f
  // [32,64) h1
  // [64,~68) weights
  float* lnx_f  = (float*)(ws + 0);
  short* lnx_b  = (short*)(ws + 8 * MB);
  short* qkv    = (short*)(ws + 12 * MB);
  short* aprt   = (short*)(ws + 24 * MB);   // A' stacked attn partials
  float* proj   = (float*)(ws + 12 * MB);
  short* r1_b   = (short*)(ws + 20 * MB);
  float* r1_f   = (float*)(ws + 24 * MB);
  short* h1     = (short*)(ws + 32 * MB);
  float* ffb    = (float*)(ws + 12 * MB);
  float* ffp1   = (float*)(ws + 0);
  short* wqkv_b = (short*)(ws + 64 * MB);
  short* wout_b = wqkv_b + 768 * 256;
  short* w1_b   = wout_b + 256 * 256;
  short* w2_b   = w1_b + 2048 * 256;

  // 1) weight converts (one kernel)
  cvt_all<<<dim3(512, 4), 256, 0, stream>>>(in_proj_w, out_proj_w, w1, w2,
                                            wqkv_b, wout_b, w1_b, w2_b);

  // 2) ln_x = LN(features)
  ln_kernel<1, 1, 1><<<2048, 256, 0, stream>>>(features, nullptr, nullptr, ln_g, ln_b, lnx_f, lnx_b);

  // 3) qkv = ln_x @ in_proj_w^T + b  (scatter q/k per-(b,h), v transposed, q scaled)
  gemm_bt<0, 64, 64, 0><<<dim3(12, 128, 1), 256, 0, stream>>>(lnx_b, wqkv_b, in_proj_b, qkv, nullptr, 256, 768, 256);

  // 4) attention (relu(tanh(qk^T)) @ v), split-K x4, bf16 partials into A'
  attn_kernel<<<dim3(16, 32, 4), 256, 0, stream>>>(qkv, qkv + 2097152, qkv + 2 * 2097152, aprt);

  // 5) proj = (sum of A' partials) @ out_proj_w^T + b   [K=1024, W wraps mod 256]
  gemm_bt<1, 64, 64, 256><<<dim3(4, 128, 1), 256, 0, stream>>>(aprt, wout_b, out_proj_b, proj, nullptr, 1024, 256, 1024);

  // 6) r1 = LN(ln_x + proj)
  ln_kernel<2, 1, 1><<<2048, 256, 0, stream>>>(lnx_f, proj, nullptr, ln_g, ln_b, r1_f, r1_b);

  // 7) h1 = relu(r1 @ w1^T + b1)
  gemm_bt<2, 128, 64, 0><<<dim3(32, 64, 1), 256, 0, stream>>>(r1_b, w1_b, b1, h1, nullptr, 256, 2048, 256);

  // 8) ff = h1 @ w2^T + b2  (split-K x2: partials in ffb, ffp1)
  gemm_bt<3, 64, 64, 0><<<dim3(4, 128, 2), 256, 0, stream>>>(h1, w2_b, b2, ffb, ffp1, 2048, 256, 1024);

  // 9) out = LN(r1 + ff0 + ff1)
  ln_kernel<3, 1, 0><<<2048, 256, 0, stream>>>(r1_f, ffb, ffp1, ln_g, ln_b, (float*)d_out, nullptr);
}